// Round 7
// baseline (158.029 us; speedup 1.0000x reference)
//
#include <hip/hip_runtime.h>
#include <stdint.h>

#define HD 512
#define NH 8
#define DH 64
#define SEQ 2048
#define BATCH 2
#define M_TOTAL (BATCH*SEQ)   // 4096
#define N_QKV (3*HD)          // 1536
#define K_DIM HD              // 512

typedef short bf16x8 __attribute__((ext_vector_type(8)));
typedef float f32x4 __attribute__((ext_vector_type(4)));
typedef uint32_t u32x2 __attribute__((ext_vector_type(2)));
typedef uint32_t u32x4 __attribute__((ext_vector_type(4)));

// q-scale: temperature 1/8 folded with log2(e) so v_exp_f32 (2^x) gives e^(s/8)
#define QSCALE 0.18033688011112042f

__device__ __forceinline__ uint16_t f2bf(float f) {
  union { float f; uint32_t u; } v; v.f = f;
  uint32_t u = v.u;
  return (uint16_t)((u + 0x7FFFu + ((u >> 16) & 1u)) >> 16);
}

__device__ __forceinline__ void gload_lds16(const void* g, void* l) {
  __builtin_amdgcn_global_load_lds(
      (const __attribute__((address_space(1))) void*)g,
      (__attribute__((address_space(3))) void*)l,
      16, 0, 0);
}

// one launch converting both x and W
__global__ void convert_all(const float* __restrict__ x, const float* __restrict__ W,
                            uint16_t* __restrict__ xb, uint16_t* __restrict__ Wb) {
  const int nx4 = M_TOTAL * K_DIM / 4;   // 524288
  const int nw4 = N_QKV * K_DIM / 4;     // 196608
  int i = blockIdx.x * 256 + threadIdx.x;
  const float* src; uint16_t* dst; int j;
  if (i < nx4) { src = x; dst = xb; j = i; }
  else { j = i - nx4; if (j >= nw4) return; src = W; dst = Wb; }
  float4 v = reinterpret_cast<const float4*>(src)[j];
  ushort4 o;
  o.x = f2bf(v.x); o.y = f2bf(v.y); o.z = f2bf(v.z); o.w = f2bf(v.w);
  reinterpret_cast<ushort4*>(dst)[j] = o;
}

// ---------------- QKV GEMM: C[4096,1536] = X[4096,512] @ W^T ----
#define BM 64
#define BN 128
#define BK 64
#define NKT (K_DIM / BK)      // 8

__global__ __launch_bounds__(256)
void qkv_gemm(const uint16_t* __restrict__ A,   // x bf16 [4096][512]
              const uint16_t* __restrict__ Bw,  // W bf16 [1536][512]
              uint16_t* __restrict__ C,         // qkv bf16 [4096][1536] (q,k parts)
              uint16_t* __restrict__ Vt) {      // [16][64][2048] bf16
  __shared__ __align__(16) uint16_t As[2][BM * BK];   // 16 KB (also V-transpose scratch)
  __shared__ __align__(16) uint16_t Bs[2][BN * BK];   // 32 KB

  const int t = threadIdx.x;
  const int lane = t & 63;
  const int w = t >> 6;
  const int l15 = lane & 15, l4 = lane >> 4;

  // XCD-aware bijective swizzle (768 blocks, 768%8==0)
  const int nbx = gridDim.x;                       // 12
  const int nwg = nbx * gridDim.y;                 // 768
  const int cpx = nwg >> 3;                        // 96
  int id = blockIdx.y * nbx + blockIdx.x;
  int wid = (id & 7) * cpx + (id >> 3);
  const int m0 = (wid / nbx) * BM;
  const int n0 = (wid % nbx) * BN;

  f32x4 acc[4][2] = {};

  auto stage = [&](int kt, int buf) {
#pragma unroll
    for (int i = 0; i < 2; ++i) {                  // A: 512 slots
      int idx = t + 256 * i;
      int row = idx >> 3, slot = idx & 7;
      int src = slot ^ (row & 7);
      gload_lds16(A + (size_t)(m0 + row) * K_DIM + kt * BK + src * 8,
                  (char*)As[buf] + idx * 16);
    }
#pragma unroll
    for (int i = 0; i < 4; ++i) {                  // B: 1024 slots
      int idx = t + 256 * i;
      int row = idx >> 3, slot = idx & 7;
      int src = slot ^ (row & 7);
      gload_lds16(Bw + (size_t)(n0 + row) * K_DIM + kt * BK + src * 8,
                  (char*)Bs[buf] + idx * 16);
    }
  };

  stage(0, 0);
  for (int kt = 0; kt < NKT; ++kt) {
    __syncthreads();                       // drains my gloads + barrier
    if (kt + 1 < NKT) stage(kt + 1, (kt + 1) & 1);
    const char* Ab = (const char*)As[kt & 1];
    const char* Bb = (const char*)Bs[kt & 1];
#pragma unroll
    for (int kk = 0; kk < 2; ++kk) {      // two K=32 sub-steps
      bf16x8 af[4], bf[2];
#pragma unroll
      for (int i = 0; i < 4; ++i) {
        int rowa = i * 16 + l15;
        int sa = (kk * 4 + l4) ^ (rowa & 7);
        af[i] = *reinterpret_cast<const bf16x8*>(Ab + rowa * 128 + sa * 16);
      }
#pragma unroll
      for (int j = 0; j < 2; ++j) {
        int rowb = w * 32 + j * 16 + l15;
        int sb = (kk * 4 + l4) ^ (rowb & 7);
        bf[j] = *reinterpret_cast<const bf16x8*>(Bb + rowb * 128 + sb * 16);
      }
#pragma unroll
      for (int i = 0; i < 4; ++i)
#pragma unroll
        for (int j = 0; j < 2; ++j)
          acc[i][j] = __builtin_amdgcn_mfma_f32_16x16x32_bf16(af[i], bf[j], acc[i][j], 0, 0, 0);
    }
  }

  // ---- epilogue ----
  const int colw = n0 + w * 32;                  // wave's 32-col slice (32-aligned)
  const int cmod = colw % 192;
  const bool isv = (cmod >= 128);                // slice entirely V
  __syncthreads();                                // LDS free: reuse As as scratch

  if (isv) {
    // transpose 64s x 32d through LDS -> coalesced 128B rows of Vt[bh][d][s]
    char* tb = (char*)As + w * 4096;             // per-wave 4 KB
#pragma unroll
    for (int i = 0; i < 4; ++i)
#pragma unroll
      for (int j = 0; j < 2; ++j) {
        uint32_t lo, hi;
        asm("v_cvt_pk_bf16_f32 %0, %1, %2" : "=v"(lo) : "v"(acc[i][j][0]), "v"(acc[i][j][1]));
        asm("v_cvt_pk_bf16_f32 %0, %1, %2" : "=v"(hi) : "v"(acc[i][j][2]), "v"(acc[i][j][3]));
        int dloc = j * 16 + l15;                 // 0..31
        int slot_s = i * 2 + (l4 >> 1);          // s>>3
        int byteoff = dloc * 128 + ((slot_s ^ (dloc & 7)) * 16) + (l4 & 1) * 8;
        u32x2 pk; pk.x = lo; pk.y = hi;
        *reinterpret_cast<u32x2*>(tb + byteoff) = pk;
      }
    int h = colw / 192;
    int d0 = cmod - 128;                          // 0 or 32
    int b = m0 >> 11;
    int sbase = m0 & (SEQ - 1);
    uint16_t* vbase = Vt + ((size_t)(b * NH + h) * DH + d0) * SEQ + sbase + (lane & 7) * 8;
#pragma unroll
    for (int p = 0; p < 4; ++p) {
      int dl = p * 8 + (lane >> 3);               // 0..31
      u32x4 rv = *reinterpret_cast<const u32x4*>(
          tb + dl * 128 + (((lane & 7) ^ (dl & 7)) * 16));
      *reinterpret_cast<u32x4*>(vbase + (size_t)dl * SEQ) = rv;
    }
  } else {
    // q (scaled) / k rows -> qkv
    float sc = ((cmod >> 6) == 0) ? QSCALE : 1.0f;
#pragma unroll
    for (int i = 0; i < 4; ++i) {
      int row = m0 + i * 16 + l4 * 4;
#pragma unroll
      for (int j = 0; j < 2; ++j) {
        int col = colw + j * 16 + l15;
#pragma unroll
        for (int jj = 0; jj < 4; ++jj)
          C[(size_t)(row + jj) * N_QKV + col] = f2bf(acc[i][j][jj] * sc);
      }
    }
  }
}

// ---------------- Flash attention, split-KV, KVBLK=32 ----
// K: global_load_lds dbuf (128B rows, XOR swizzle, conflict-free).
// V: per-wave direct global->reg fragments (L2-resident; no LDS, no conflicts).
// P: per-wave LDS, 80B padded rows (2-way banks = free).
#define KVB 32
#define NT2 (SEQ / KVB)        // 64 kv tiles total
#define PLS 80                 // P row stride bytes (64 data + 16 pad)

__global__ __launch_bounds__(256, 5)
void attn(const uint16_t* __restrict__ qkv, const uint16_t* __restrict__ VtG,
          float* __restrict__ Po,      // [split][16][2048][64] f32 unnormalized
          float2* __restrict__ Pml) {  // [split][16][2048] (m, l)
  __shared__ __align__(16) uint16_t Kt[2][KVB * 64];   // 4 KB each
  __shared__ __align__(16) uint8_t Pl[4][16 * PLS];    // 1.25 KB per wave

  const int t = threadIdx.x;
  const int lane = t & 63;
  const int w = t >> 6;
  const int l15 = lane & 15, l4 = lane >> 4;
  const int bh = blockIdx.x;               // head-major: XCD bh%8 owns 2 heads' K/V
  const int b = bh >> 3, h = bh & 7;
  const int qw = blockIdx.y * 64 + w * 16;
  const int half = blockIdx.z;
  const int tph = NT2 / gridDim.z;
  const int t0 = half * tph;

  // Q fragments (pre-scaled by QSCALE in GEMM epilogue)
  bf16x8 qf[2];
  {
    const uint16_t* qp = qkv + (size_t)(b * SEQ + qw + l15) * N_QKV + h * 192;
#pragma unroll
    for (int kk = 0; kk < 2; ++kk)
      qf[kk] = *reinterpret_cast<const bf16x8*>(qp + kk * 32 + l4 * 8);
  }

  const uint16_t* kgbase = qkv + (size_t)b * SEQ * N_QKV + h * 192 + 64;
  const uint16_t* vgbase = VtG + (size_t)bh * DH * SEQ;

  // K stage: 1 gload_lds per thread (32 rows x 128B)
  auto stageK = [&](int ti, int buf) {
    int s0 = ti * KVB;
    int row = t >> 3, slot = t & 7;
    int src = slot ^ (row & 7);
    gload_lds16(kgbase + (size_t)(s0 + row) * N_QKV + src * 8,
                (char*)Kt[buf] + t * 16);
  };

  f32x4 ot[4] = {};                        // O^T: ot[f][jj] = O[d=f*16+l4*4+jj][q=l15]
  float mrow = -1e30f, lrow = 0.0f;        // per-lane state for q = qw + l15

  stageK(t0, 0);
  for (int rel = 0; rel < tph; ++rel) {
    __syncthreads();                       // vmcnt(0) drain + barrier: K(rel) ready
    int s0 = (t0 + rel) * KVB;

    // V fragments for THIS tile straight to regs (consumed after softmax)
    bf16x8 vf[4];
#pragma unroll
    for (int f = 0; f < 4; ++f)
      vf[f] = *reinterpret_cast<const bf16x8*>(
          vgbase + (size_t)(f * 16 + l15) * SEQ + s0 + l4 * 8);

    if (rel + 1 < tph) stageK(t0 + rel + 1, (rel + 1) & 1);
    const char* Kb = (const char*)Kt[rel & 1];

    // S^T = K @ Q^T : s[c] rows = key c*16+l4*4+jj, col = q = l15
    f32x4 s[2] = {};
    __builtin_amdgcn_s_setprio(1);
#pragma unroll
    for (int c = 0; c < 2; ++c) {
#pragma unroll
      for (int kk = 0; kk < 2; ++kk) {
        int row = c * 16 + l15;
        int sl = (kk * 4 + l4) ^ (row & 7);
        bf16x8 kf = *reinterpret_cast<const bf16x8*>(Kb + row * 128 + sl * 16);
        s[c] = __builtin_amdgcn_mfma_f32_16x16x32_bf16(kf, qf[kk], s[c], 0, 0, 0);
      }
    }
    __builtin_amdgcn_s_setprio(0);

    // lane-local softmax for q=l15: 8 in-lane keys + 2 cross-lane steps
    float vmax = s[0][0];
#pragma unroll
    for (int c = 0; c < 2; ++c)
#pragma unroll
      for (int jj = 0; jj < 4; ++jj) vmax = fmaxf(vmax, s[c][jj]);
    vmax = fmaxf(vmax, __shfl_xor(vmax, 16, 64));
    vmax = fmaxf(vmax, __shfl_xor(vmax, 32, 64));

    if (!__all(vmax - mrow <= 11.0f)) {    // defer-max (log2 domain)
      float mn = fmaxf(mrow, vmax);
      float sc;
      float darg = mrow - mn;
      asm("v_exp_f32 %0, %1" : "=v"(sc) : "v"(darg));
      mrow = mn;
#pragma unroll
      for (int f = 0; f < 4; ++f)
#pragma unroll
        for (int jj = 0; jj < 4; ++jj) ot[f][jj] *= sc;   // lane-local, no shfl
      lrow *= sc;
    }

    float p[8];
#pragma unroll
    for (int c = 0; c < 2; ++c)
#pragma unroll
      for (int jj = 0; jj < 4; ++jj) {
        float arg = s[c][jj] - mrow;
        float e;
        asm("v_exp_f32 %0, %1" : "=v"(e) : "v"(arg));   // 2^x (log2-domain scores)
        p[c * 4 + jj] = e;
      }
    float tsum = ((p[0] + p[1]) + (p[2] + p[3])) + ((p[4] + p[5]) + (p[6] + p[7]));
    tsum += __shfl_xor(tsum, 16, 64);
    tsum += __shfl_xor(tsum, 32, 64);
    lrow += tsum;

    // pack P (keys 16c+4*l4+jj), one b64 store per c; padded 80B rows -> 2-way banks
#pragma unroll
    for (int c = 0; c < 2; ++c) {
      uint32_t lo, hi;
      asm("v_cvt_pk_bf16_f32 %0, %1, %2" : "=v"(lo) : "v"(p[c * 4 + 0]), "v"(p[c * 4 + 1]));
      asm("v_cvt_pk_bf16_f32 %0, %1, %2" : "=v"(hi) : "v"(p[c * 4 + 2]), "v"(p[c * 4 + 3]));
      int slot = 2 * c + (l4 >> 1);
      int byteoff = l15 * PLS + slot * 16 + (l4 & 1) * 8;
      u32x2 pk; pk.x = lo; pk.y = hi;
      *reinterpret_cast<u32x2*>((char*)Pl[w] + byteoff) = pk;
    }

    // O^T += V @ P^T : A = vf (row=d, k=key), B = pa (col=q, k=key)
    bf16x8 pa = *reinterpret_cast<const bf16x8*>((const char*)Pl[w] + l15 * PLS + l4 * 16);
    __builtin_amdgcn_s_setprio(1);
#pragma unroll
    for (int f = 0; f < 4; ++f)
      ot[f] = __builtin_amdgcn_mfma_f32_16x16x32_bf16(vf[f], pa, ot[f], 0, 0, 0);
    __builtin_amdgcn_s_setprio(0);
  }

  // write partials: coalesced f32x4 (4 consecutive d per reg)
  float* pob = Po + ((size_t)(half * 16 + bh) * SEQ) * DH + (size_t)(qw + l15) * DH;
#pragma unroll
  for (int f = 0; f < 4; ++f)
    *reinterpret_cast<f32x4*>(pob + f * 16 + l4 * 4) = ot[f];
  if (lane < 16) {
    float2 ml; ml.x = mrow; ml.y = lrow;
    Pml[(size_t)(half * 16 + bh) * SEQ + qw + lane] = ml;
  }
}

// ---------------- combine partials -> out[b][q][h*64+d] ----
__global__ __launch_bounds__(256)
void attn_combine(const float* __restrict__ Po, const float2* __restrict__ Pml,
                  float* __restrict__ out, int nsplit) {
  int idx = blockIdx.x * 256 + threadIdx.x;   // 16bh * 2048q * 16 d4
  int d4 = idx & 15;
  int q = (idx >> 4) & (SEQ - 1);
  int bh = idx >> 15;
  int b = bh >> 3, h = bh & 7;

  float m = -1e30f;
  for (int s = 0; s < nsplit; ++s)
    m = fmaxf(m, Pml[(size_t)(s * 16 + bh) * SEQ + q].x);
  float den = 0.0f;
  f32x4 acc = {};
  for (int s = 0; s < nsplit; ++s) {
    float2 ml = Pml[(size_t)(s * 16 + bh) * SEQ + q];
    float a = exp2f(ml.x - m);
    den += ml.y * a;
    f32x4 ov = *reinterpret_cast<const f32x4*>(
        Po + ((size_t)(s * 16 + bh) * SEQ + q) * DH + d4 * 4);
#pragma unroll
    for (int i = 0; i < 4; ++i) acc[i] += ov[i] * a;
  }
  float rden = 1.0f / den;
  f32x4 res;
#pragma unroll
  for (int i = 0; i < 4; ++i) res[i] = acc[i] * rden;
  *reinterpret_cast<f32x4*>(out + ((size_t)(b * SEQ + q) * HD) + h * 64 + d4 * 4) = res;
}

extern "C" void kernel_launch(void* const* d_in, const int* in_sizes, int n_in,
                              void* d_out, int out_size, void* d_ws, size_t ws_size,
                              hipStream_t stream) {
  const float* x = (const float*)d_in[0];
  const float* Wq = (const float*)d_in[1];
  float* out = (float*)d_out;

  uint16_t* xb = (uint16_t*)d_ws;                       // 4096*512 bf16   (4 MB)
  uint16_t* Wb = xb + (size_t)M_TOTAL * K_DIM;          // 1536*512 bf16   (1.5 MB)
  uint16_t* qkv = Wb + (size_t)N_QKV * K_DIM;           // 4096*1536 bf16  (12.6 MB)
  uint16_t* vtg = qkv + (size_t)M_TOTAL * N_QKV;        // 16*64*2048 bf16 (4 MB)
  float* Po = (float*)(vtg + (size_t)16 * DH * SEQ);    // 4*16*2048*64 f32 (33.6 MB)
  float2* Pml = (float2*)(Po + (size_t)4 * 16 * SEQ * DH);  // 4*16*2048 f32x2 (1 MB)
  size_t base = (size_t)((char*)Po - (char*)d_ws);
  size_t per_split = (size_t)16 * SEQ * DH * 4 + (size_t)16 * SEQ * 8;
  int nsplit = 1;
  if (ws_size >= base + 4 * per_split) nsplit = 4;
  else if (ws_size >= base + 2 * per_split) nsplit = 2;

  convert_all<<<(M_TOTAL * K_DIM / 4 + N_QKV * K_DIM / 4 + 255) / 256, 256, 0, stream>>>(
      x, Wq, xb, Wb);

  dim3 g1(N_QKV / BN, M_TOTAL / BM);
  qkv_gemm<<<g1, 256, 0, stream>>>(xb, Wb, qkv, vtg);

  dim3 g2(BATCH * NH, SEQ / 64, nsplit);
  attn<<<g2, 256, 0, stream>>>(qkv, vtg, Po, Pml);

  attn_combine<<<(16 * SEQ * 16) / 256, 256, 0, stream>>>(Po, Pml, out, nsplit);
}

// Round 8
// 114.425 us; speedup vs baseline: 1.3811x; 1.3811x over previous
//
#include <hip/hip_runtime.h>
#include <stdint.h>

#define HD 512
#define NH 8
#define DH 64
#define SEQ 2048
#define BATCH 2
#define M_TOTAL (BATCH*SEQ)   // 4096
#define N_QKV (3*HD)          // 1536
#define K_DIM HD              // 512

typedef short bf16x8 __attribute__((ext_vector_type(8)));
typedef float f32x4 __attribute__((ext_vector_type(4)));
typedef uint32_t u32x2 __attribute__((ext_vector_type(2)));
typedef uint32_t u32x4 __attribute__((ext_vector_type(4)));

// q-scale: temperature 1/8 folded with log2(e) so v_exp_f32 (2^x) gives e^(s/8)
#define QSCALE 0.18033688011112042f

__device__ __forceinline__ uint16_t f2bf(float f) {
  union { float f; uint32_t u; } v; v.f = f;
  uint32_t u = v.u;
  return (uint16_t)((u + 0x7FFFu + ((u >> 16) & 1u)) >> 16);
}

__device__ __forceinline__ void gload_lds16(const void* g, void* l) {
  __builtin_amdgcn_global_load_lds(
      (const __attribute__((address_space(1))) void*)g,
      (__attribute__((address_space(3))) void*)l,
      16, 0, 0);
}

// one launch converting both x and W
__global__ void convert_all(const float* __restrict__ x, const float* __restrict__ W,
                            uint16_t* __restrict__ xb, uint16_t* __restrict__ Wb) {
  const int nx4 = M_TOTAL * K_DIM / 4;   // 524288
  const int nw4 = N_QKV * K_DIM / 4;     // 196608
  int i = blockIdx.x * 256 + threadIdx.x;
  const float* src; uint16_t* dst; int j;
  if (i < nx4) { src = x; dst = xb; j = i; }
  else { j = i - nx4; if (j >= nw4) return; src = W; dst = Wb; }
  float4 v = reinterpret_cast<const float4*>(src)[j];
  ushort4 o;
  o.x = f2bf(v.x); o.y = f2bf(v.y); o.z = f2bf(v.z); o.w = f2bf(v.w);
  reinterpret_cast<ushort4*>(dst)[j] = o;
}

// ---------------- QKV GEMM: C[4096,1536] = X[4096,512] @ W^T ----
#define BM 64
#define BN 128
#define BK 64
#define NKT (K_DIM / BK)      // 8

__global__ __launch_bounds__(256)
void qkv_gemm(const uint16_t* __restrict__ A,   // x bf16 [4096][512]
              const uint16_t* __restrict__ Bw,  // W bf16 [1536][512]
              uint16_t* __restrict__ C,         // qkv bf16 [4096][1536] (q,k parts)
              uint16_t* __restrict__ Vt) {      // [16][64][2048] bf16
  __shared__ __align__(16) uint16_t As[2][BM * BK];   // 16 KB (also V-transpose scratch)
  __shared__ __align__(16) uint16_t Bs[2][BN * BK];   // 32 KB

  const int t = threadIdx.x;
  const int lane = t & 63;
  const int w = t >> 6;
  const int l15 = lane & 15, l4 = lane >> 4;

  // XCD-aware bijective swizzle (768 blocks, 768%8==0)
  const int nbx = gridDim.x;                       // 12
  const int nwg = nbx * gridDim.y;                 // 768
  const int cpx = nwg >> 3;                        // 96
  int id = blockIdx.y * nbx + blockIdx.x;
  int wid = (id & 7) * cpx + (id >> 3);
  const int m0 = (wid / nbx) * BM;
  const int n0 = (wid % nbx) * BN;

  f32x4 acc[4][2] = {};

  auto stage = [&](int kt, int buf) {
#pragma unroll
    for (int i = 0; i < 2; ++i) {                  // A: 512 slots
      int idx = t + 256 * i;
      int row = idx >> 3, slot = idx & 7;
      int src = slot ^ (row & 7);
      gload_lds16(A + (size_t)(m0 + row) * K_DIM + kt * BK + src * 8,
                  (char*)As[buf] + idx * 16);
    }
#pragma unroll
    for (int i = 0; i < 4; ++i) {                  // B: 1024 slots
      int idx = t + 256 * i;
      int row = idx >> 3, slot = idx & 7;
      int src = slot ^ (row & 7);
      gload_lds16(Bw + (size_t)(n0 + row) * K_DIM + kt * BK + src * 8,
                  (char*)Bs[buf] + idx * 16);
    }
  };

  stage(0, 0);
  for (int kt = 0; kt < NKT; ++kt) {
    __syncthreads();                       // drains my gloads + barrier
    if (kt + 1 < NKT) stage(kt + 1, (kt + 1) & 1);
    const char* Ab = (const char*)As[kt & 1];
    const char* Bb = (const char*)Bs[kt & 1];
#pragma unroll
    for (int kk = 0; kk < 2; ++kk) {      // two K=32 sub-steps
      bf16x8 af[4], bf[2];
#pragma unroll
      for (int i = 0; i < 4; ++i) {
        int rowa = i * 16 + l15;
        int sa = (kk * 4 + l4) ^ (rowa & 7);
        af[i] = *reinterpret_cast<const bf16x8*>(Ab + rowa * 128 + sa * 16);
      }
#pragma unroll
      for (int j = 0; j < 2; ++j) {
        int rowb = w * 32 + j * 16 + l15;
        int sb = (kk * 4 + l4) ^ (rowb & 7);
        bf[j] = *reinterpret_cast<const bf16x8*>(Bb + rowb * 128 + sb * 16);
      }
#pragma unroll
      for (int i = 0; i < 4; ++i)
#pragma unroll
        for (int j = 0; j < 2; ++j)
          acc[i][j] = __builtin_amdgcn_mfma_f32_16x16x32_bf16(af[i], bf[j], acc[i][j], 0, 0, 0);
    }
  }

  // ---- epilogue ----
  const int colw = n0 + w * 32;                  // wave's 32-col slice (32-aligned)
  const int cmod = colw % 192;
  const bool isv = (cmod >= 128);                // slice entirely V
  __syncthreads();                                // LDS free: reuse As as scratch

  if (isv) {
    // transpose 64s x 32d through LDS -> coalesced 128B rows of Vt[bh][d][s]
    char* tb = (char*)As + w * 4096;             // per-wave 4 KB
#pragma unroll
    for (int i = 0; i < 4; ++i)
#pragma unroll
      for (int j = 0; j < 2; ++j) {
        uint32_t lo, hi;
        asm("v_cvt_pk_bf16_f32 %0, %1, %2" : "=v"(lo) : "v"(acc[i][j][0]), "v"(acc[i][j][1]));
        asm("v_cvt_pk_bf16_f32 %0, %1, %2" : "=v"(hi) : "v"(acc[i][j][2]), "v"(acc[i][j][3]));
        int dloc = j * 16 + l15;                 // 0..31
        int slot_s = i * 2 + (l4 >> 1);          // s>>3
        int byteoff = dloc * 128 + ((slot_s ^ (dloc & 7)) * 16) + (l4 & 1) * 8;
        u32x2 pk; pk.x = lo; pk.y = hi;
        *reinterpret_cast<u32x2*>(tb + byteoff) = pk;
      }
    int h = colw / 192;
    int d0 = cmod - 128;                          // 0 or 32
    int b = m0 >> 11;
    int sbase = m0 & (SEQ - 1);
    uint16_t* vbase = Vt + ((size_t)(b * NH + h) * DH + d0) * SEQ + sbase + (lane & 7) * 8;
#pragma unroll
    for (int p = 0; p < 4; ++p) {
      int dl = p * 8 + (lane >> 3);               // 0..31
      u32x4 rv = *reinterpret_cast<const u32x4*>(
          tb + dl * 128 + (((lane & 7) ^ (dl & 7)) * 16));
      *reinterpret_cast<u32x4*>(vbase + (size_t)dl * SEQ) = rv;
    }
  } else {
    // q (scaled) / k rows -> qkv
    float sc = ((cmod >> 6) == 0) ? QSCALE : 1.0f;
#pragma unroll
    for (int i = 0; i < 4; ++i) {
      int row = m0 + i * 16 + l4 * 4;
#pragma unroll
      for (int j = 0; j < 2; ++j) {
        int col = colw + j * 16 + l15;
#pragma unroll
        for (int jj = 0; jj < 4; ++jj)
          C[(size_t)(row + jj) * N_QKV + col] = f2bf(acc[i][j][jj] * sc);
      }
    }
  }
}

// ---------------- Flash attention, split-KV, KVBLK=64 (R4 skeleton) ----
// K,V: global_load_lds double-buffer, 128B swizzled rows (0-conflict).
// One __syncthreads per tile. PV transposed -> lane-local rescale + f32x4 Po.
#define NT (SEQ / 64)          // 32 kv tiles total

__global__ __launch_bounds__(256)
void attn(const uint16_t* __restrict__ qkv, const uint16_t* __restrict__ VtG,
          float* __restrict__ Po,      // [split][16][2048][64] f32 unnormalized
          float2* __restrict__ Pml) {  // [split][16][2048] (m, l)
  __shared__ __align__(16) uint16_t Kt[2][64 * 64];   // [key][d] swizzled (8 KB ea)
  __shared__ __align__(16) uint16_t Vt[2][64 * 64];   // [d][key] swizzled (8 KB ea)
  __shared__ __align__(16) uint16_t Pl[4][16 * 64];   // per-wave [q][key] swizzled (2 KB ea)

  const int t = threadIdx.x;
  const int lane = t & 63;
  const int w = t >> 6;
  const int l15 = lane & 15, l4 = lane >> 4;
  const int bh = blockIdx.x;               // head-major: XCD bh%8 owns 2 heads' K/V
  const int b = bh >> 3, h = bh & 7;
  const int qw = blockIdx.y * 64 + w * 16;
  const int half = blockIdx.z;
  const int tph = NT / gridDim.z;
  const int t0 = half * tph;

  // Q fragments (pre-scaled by QSCALE in GEMM epilogue)
  bf16x8 qf[2];
  {
    const uint16_t* qp = qkv + (size_t)(b * SEQ + qw + l15) * N_QKV + h * 192;
#pragma unroll
    for (int kk = 0; kk < 2; ++kk)
      qf[kk] = *reinterpret_cast<const bf16x8*>(qp + kk * 32 + l4 * 8);
  }

  const uint16_t* kgbase = qkv + (size_t)b * SEQ * N_QKV + h * 192 + 64;
  const uint16_t* vgbase = VtG + (size_t)bh * DH * SEQ;

  auto stage = [&](int ti, int buf) {
    int s0 = ti * 64;
#pragma unroll
    for (int i = 0; i < 2; ++i) {
      int idx = t + 256 * i;
      int row = idx >> 3, slot = idx & 7;
      int src = slot ^ (row & 7);
      gload_lds16(kgbase + (size_t)(s0 + row) * N_QKV + src * 8,
                  (char*)Kt[buf] + idx * 16);
      gload_lds16(vgbase + (size_t)row * SEQ + s0 + src * 8,
                  (char*)Vt[buf] + idx * 16);
    }
  };

  f32x4 ot[4] = {};                        // ot[f][jj] = O[d=f*16+l4*4+jj][q=l15]
  float mrow = -1e30f, lrow = 0.0f;        // per-lane state for q = qw + l15

  stage(t0, 0);
  for (int rel = 0; rel < tph; ++rel) {
    __syncthreads();                       // vmcnt(0) drain + barrier: tile rel ready
    if (rel + 1 < tph) stage(t0 + rel + 1, (rel + 1) & 1);
    const char* Kb = (const char*)Kt[rel & 1];
    const char* Vb = (const char*)Vt[rel & 1];

    // S^T = K @ Q^T : s[c] rows = key c*16+l4*4+jj, col = q = l15
    f32x4 s[4] = {};
    __builtin_amdgcn_s_setprio(1);
#pragma unroll
    for (int c = 0; c < 4; ++c) {
#pragma unroll
      for (int kk = 0; kk < 2; ++kk) {
        int row = c * 16 + l15;
        int sl = (kk * 4 + l4) ^ (row & 7);
        bf16x8 kf = *reinterpret_cast<const bf16x8*>(Kb + row * 128 + sl * 16);
        s[c] = __builtin_amdgcn_mfma_f32_16x16x32_bf16(kf, qf[kk], s[c], 0, 0, 0);
      }
    }
    __builtin_amdgcn_s_setprio(0);

    // lane-local softmax for q=l15: 16 in-lane keys + 2 cross-lane steps
    float vmax = s[0][0];
#pragma unroll
    for (int c = 0; c < 4; ++c)
#pragma unroll
      for (int jj = 0; jj < 4; ++jj) vmax = fmaxf(vmax, s[c][jj]);
    vmax = fmaxf(vmax, __shfl_xor(vmax, 16, 64));
    vmax = fmaxf(vmax, __shfl_xor(vmax, 32, 64));

    if (!__all(vmax - mrow <= 11.0f)) {    // defer-max (log2 domain)
      float mn = fmaxf(mrow, vmax);
      float sc;
      float darg = mrow - mn;
      asm("v_exp_f32 %0, %1" : "=v"(sc) : "v"(darg));
      mrow = mn;
#pragma unroll
      for (int f = 0; f < 4; ++f)
#pragma unroll
        for (int jj = 0; jj < 4; ++jj) ot[f][jj] *= sc;   // lane-local, no shfl
      lrow *= sc;
    }

    float p[16];
#pragma unroll
    for (int c = 0; c < 4; ++c)
#pragma unroll
      for (int jj = 0; jj < 4; ++jj) {
        float arg = s[c][jj] - mrow;
        float e;
        asm("v_exp_f32 %0, %1" : "=v"(e) : "v"(arg));   // 2^x (log2-domain scores)
        p[c * 4 + jj] = e;
      }
    float a0 = (p[0] + p[1]) + (p[2] + p[3]);
    float a1 = (p[4] + p[5]) + (p[6] + p[7]);
    float a2 = (p[8] + p[9]) + (p[10] + p[11]);
    float a3 = (p[12] + p[13]) + (p[14] + p[15]);
    float tsum = (a0 + a1) + (a2 + a3);
    tsum += __shfl_xor(tsum, 16, 64);
    tsum += __shfl_xor(tsum, 32, 64);
    lrow += tsum;

    // pack P (4 consecutive keys per c), one b64 store per c (swizzled 128B rows)
#pragma unroll
    for (int c = 0; c < 4; ++c) {
      uint32_t lo, hi;
      asm("v_cvt_pk_bf16_f32 %0, %1, %2" : "=v"(lo) : "v"(p[c * 4 + 0]), "v"(p[c * 4 + 1]));
      asm("v_cvt_pk_bf16_f32 %0, %1, %2" : "=v"(hi) : "v"(p[c * 4 + 2]), "v"(p[c * 4 + 3]));
      int slot = 2 * c + (l4 >> 1);
      int byteoff = l15 * 128 + ((slot ^ (l15 & 7)) * 16) + (l4 & 1) * 8;
      u32x2 pk; pk.x = lo; pk.y = hi;
      *reinterpret_cast<u32x2*>((char*)Pl[w] + byteoff) = pk;
    }

    // O^T += V @ P^T : A = vf (row=d), B = pa (col=q)  [same LDS reads as R4]
    __builtin_amdgcn_s_setprio(1);
#pragma unroll
    for (int kk = 0; kk < 2; ++kk) {
      int sp = (kk * 4 + l4) ^ (l15 & 7);
      bf16x8 pa = *reinterpret_cast<const bf16x8*>((const char*)Pl[w] + l15 * 128 + sp * 16);
#pragma unroll
      for (int f = 0; f < 4; ++f) {
        int d = f * 16 + l15;
        int sv = (kk * 4 + l4) ^ (d & 7);
        bf16x8 vf = *reinterpret_cast<const bf16x8*>(Vb + d * 128 + sv * 16);
        ot[f] = __builtin_amdgcn_mfma_f32_16x16x32_bf16(vf, pa, ot[f], 0, 0, 0);
      }
    }
    __builtin_amdgcn_s_setprio(0);
  }

  // write partials: coalesced f32x4 (4 consecutive d per reg)
  float* pob = Po + ((size_t)(half * 16 + bh) * SEQ) * DH + (size_t)(qw + l15) * DH;
#pragma unroll
  for (int f = 0; f < 4; ++f)
    *reinterpret_cast<f32x4*>(pob + f * 16 + l4 * 4) = ot[f];
  if (lane < 16) {
    float2 ml; ml.x = mrow; ml.y = lrow;
    Pml[(size_t)(half * 16 + bh) * SEQ + qw + lane] = ml;
  }
}

// ---------------- combine partials -> out[b][q][h*64+d] ----
__global__ __launch_bounds__(256)
void attn_combine(const float* __restrict__ Po, const float2* __restrict__ Pml,
                  float* __restrict__ out, int nsplit) {
  int idx = blockIdx.x * 256 + threadIdx.x;   // 16bh * 2048q * 16 d4
  int d4 = idx & 15;
  int q = (idx >> 4) & (SEQ - 1);
  int bh = idx >> 15;
  int b = bh >> 3, h = bh & 7;

  float m = -1e30f;
  for (int s = 0; s < nsplit; ++s)
    m = fmaxf(m, Pml[(size_t)(s * 16 + bh) * SEQ + q].x);
  float den = 0.0f;
  f32x4 acc = {};
  for (int s = 0; s < nsplit; ++s) {
    float2 ml = Pml[(size_t)(s * 16 + bh) * SEQ + q];
    float a = exp2f(ml.x - m);
    den += ml.y * a;
    f32x4 ov = *reinterpret_cast<const f32x4*>(
        Po + ((size_t)(s * 16 + bh) * SEQ + q) * DH + d4 * 4);
#pragma unroll
    for (int i = 0; i < 4; ++i) acc[i] += ov[i] * a;
  }
  float rden = 1.0f / den;
  f32x4 res;
#pragma unroll
  for (int i = 0; i < 4; ++i) res[i] = acc[i] * rden;
  *reinterpret_cast<f32x4*>(out + ((size_t)(b * SEQ + q) * HD) + h * 64 + d4 * 4) = res;
}

extern "C" void kernel_launch(void* const* d_in, const int* in_sizes, int n_in,
                              void* d_out, int out_size, void* d_ws, size_t ws_size,
                              hipStream_t stream) {
  const float* x = (const float*)d_in[0];
  const float* Wq = (const float*)d_in[1];
  float* out = (float*)d_out;

  uint16_t* xb = (uint16_t*)d_ws;                       // 4096*512 bf16   (4 MB)
  uint16_t* Wb = xb + (size_t)M_TOTAL * K_DIM;          // 1536*512 bf16   (1.5 MB)
  uint16_t* qkv = Wb + (size_t)N_QKV * K_DIM;           // 4096*1536 bf16  (12.6 MB)
  uint16_t* vtg = qkv + (size_t)M_TOTAL * N_QKV;        // 16*64*2048 bf16 (4 MB)
  float* Po = (float*)(vtg + (size_t)16 * DH * SEQ);    // 2*16*2048*64 f32 (16.8 MB)
  float2* Pml = (float2*)(Po + (size_t)2 * 16 * SEQ * DH);  // 2*16*2048 f32x2 (0.5 MB)
  size_t base = (size_t)((char*)Po - (char*)d_ws);
  size_t per_split = (size_t)16 * SEQ * DH * 4 + (size_t)16 * SEQ * 8;
  int nsplit = (ws_size >= base + 2 * per_split) ? 2 : 1;

  convert_all<<<(M_TOTAL * K_DIM / 4 + N_QKV * K_DIM / 4 + 255) / 256, 256, 0, stream>>>(
      x, Wq, xb, Wb);

  dim3 g1(N_QKV / BN, M_TOTAL / BM);
  qkv_gemm<<<g1, 256, 0, stream>>>(xb, Wb, qkv, vtg);

  dim3 g2(BATCH * NH, SEQ / 64, nsplit);
  attn<<<g2, 256, 0, stream>>>(qkv, vtg, Po, Pml);

  attn_combine<<<(16 * SEQ * 16) / 256, 256, 0, stream>>>(Po, Pml, out, nsplit);
}

// Round 10
// 110.860 us; speedup vs baseline: 1.4255x; 1.0322x over previous
//
#include <hip/hip_runtime.h>
#include <stdint.h>

#define HD 512
#define NH 8
#define DH 64
#define SEQ 2048
#define BATCH 2
#define M_TOTAL (BATCH*SEQ)   // 4096
#define N_QKV (3*HD)          // 1536
#define K_DIM HD              // 512

typedef short bf16x8 __attribute__((ext_vector_type(8)));
typedef float f32x4 __attribute__((ext_vector_type(4)));
typedef uint32_t u32x2 __attribute__((ext_vector_type(2)));
typedef uint32_t u32x4 __attribute__((ext_vector_type(4)));

// q-scale: temperature 1/8 folded with log2(e) so v_exp_f32 (2^x) gives e^(s/8)
#define QSCALE 0.18033688011112042f

__device__ __forceinline__ uint16_t f2bf(float f) {
  union { float f; uint32_t u; } v; v.f = f;
  uint32_t u = v.u;
  return (uint16_t)((u + 0x7FFFu + ((u >> 16) & 1u)) >> 16);
}

__device__ __forceinline__ void gload_lds16(const void* g, void* l) {
  __builtin_amdgcn_global_load_lds(
      (const __attribute__((address_space(1))) void*)g,
      (__attribute__((address_space(3))) void*)l,
      16, 0, 0);
}

// one launch converting both x and W
__global__ void convert_all(const float* __restrict__ x, const float* __restrict__ W,
                            uint16_t* __restrict__ xb, uint16_t* __restrict__ Wb) {
  const int nx4 = M_TOTAL * K_DIM / 4;   // 524288
  const int nw4 = N_QKV * K_DIM / 4;     // 196608
  int i = blockIdx.x * 256 + threadIdx.x;
  const float* src; uint16_t* dst; int j;
  if (i < nx4) { src = x; dst = xb; j = i; }
  else { j = i - nx4; if (j >= nw4) return; src = W; dst = Wb; }
  float4 v = reinterpret_cast<const float4*>(src)[j];
  ushort4 o;
  o.x = f2bf(v.x); o.y = f2bf(v.y); o.z = f2bf(v.z); o.w = f2bf(v.w);
  reinterpret_cast<ushort4*>(dst)[j] = o;
}

// ---------------- QKV GEMM: C[4096,1536] = X[4096,512] @ W^T ----
#define BM 64
#define BN 128
#define BK 64
#define NKT (K_DIM / BK)      // 8

__global__ __launch_bounds__(256)
void qkv_gemm(const uint16_t* __restrict__ A,   // x bf16 [4096][512]
              const uint16_t* __restrict__ Bw,  // W bf16 [1536][512]
              uint16_t* __restrict__ C,         // qkv bf16 [4096][1536] (q,k parts)
              uint16_t* __restrict__ Vt) {      // [16][64][2048] bf16
  __shared__ __align__(16) uint16_t As[2][BM * BK];   // 16 KB (also V-transpose scratch)
  __shared__ __align__(16) uint16_t Bs[2][BN * BK];   // 32 KB

  const int t = threadIdx.x;
  const int lane = t & 63;
  const int w = t >> 6;
  const int l15 = lane & 15, l4 = lane >> 4;

  // XCD-aware bijective swizzle (768 blocks, 768%8==0)
  const int nbx = gridDim.x;                       // 12
  const int nwg = nbx * gridDim.y;                 // 768
  const int cpx = nwg >> 3;                        // 96
  int id = blockIdx.y * nbx + blockIdx.x;
  int wid = (id & 7) * cpx + (id >> 3);
  const int m0 = (wid / nbx) * BM;
  const int n0 = (wid % nbx) * BN;

  f32x4 acc[4][2] = {};

  auto stage = [&](int kt, int buf) {
#pragma unroll
    for (int i = 0; i < 2; ++i) {                  // A: 512 slots
      int idx = t + 256 * i;
      int row = idx >> 3, slot = idx & 7;
      int src = slot ^ (row & 7);
      gload_lds16(A + (size_t)(m0 + row) * K_DIM + kt * BK + src * 8,
                  (char*)As[buf] + idx * 16);
    }
#pragma unroll
    for (int i = 0; i < 4; ++i) {                  // B: 1024 slots
      int idx = t + 256 * i;
      int row = idx >> 3, slot = idx & 7;
      int src = slot ^ (row & 7);
      gload_lds16(Bw + (size_t)(n0 + row) * K_DIM + kt * BK + src * 8,
                  (char*)Bs[buf] + idx * 16);
    }
  };

  stage(0, 0);
  for (int kt = 0; kt < NKT; ++kt) {
    __syncthreads();                       // drains my gloads + barrier
    if (kt + 1 < NKT) stage(kt + 1, (kt + 1) & 1);
    const char* Ab = (const char*)As[kt & 1];
    const char* Bb = (const char*)Bs[kt & 1];
#pragma unroll
    for (int kk = 0; kk < 2; ++kk) {      // two K=32 sub-steps
      bf16x8 af[4], bf[2];
#pragma unroll
      for (int i = 0; i < 4; ++i) {
        int rowa = i * 16 + l15;
        int sa = (kk * 4 + l4) ^ (rowa & 7);
        af[i] = *reinterpret_cast<const bf16x8*>(Ab + rowa * 128 + sa * 16);
      }
#pragma unroll
      for (int j = 0; j < 2; ++j) {
        int rowb = w * 32 + j * 16 + l15;
        int sb = (kk * 4 + l4) ^ (rowb & 7);
        bf[j] = *reinterpret_cast<const bf16x8*>(Bb + rowb * 128 + sb * 16);
      }
#pragma unroll
      for (int i = 0; i < 4; ++i)
#pragma unroll
        for (int j = 0; j < 2; ++j)
          acc[i][j] = __builtin_amdgcn_mfma_f32_16x16x32_bf16(af[i], bf[j], acc[i][j], 0, 0, 0);
    }
  }

  // ---- epilogue ----
  const int colw = n0 + w * 32;                  // wave's 32-col slice (32-aligned)
  const int cmod = colw % 192;
  const bool isv = (cmod >= 128);                // slice entirely V
  __syncthreads();                                // LDS free: reuse As as scratch

  if (isv) {
    // transpose 64s x 32d through LDS -> coalesced 128B rows of Vt[bh][d][s]
    char* tb = (char*)As + w * 4096;             // per-wave 4 KB
#pragma unroll
    for (int i = 0; i < 4; ++i)
#pragma unroll
      for (int j = 0; j < 2; ++j) {
        uint32_t lo, hi;
        asm("v_cvt_pk_bf16_f32 %0, %1, %2" : "=v"(lo) : "v"(acc[i][j][0]), "v"(acc[i][j][1]));
        asm("v_cvt_pk_bf16_f32 %0, %1, %2" : "=v"(hi) : "v"(acc[i][j][2]), "v"(acc[i][j][3]));
        int dloc = j * 16 + l15;                 // 0..31
        int slot_s = i * 2 + (l4 >> 1);          // s>>3
        int byteoff = dloc * 128 + ((slot_s ^ (dloc & 7)) * 16) + (l4 & 1) * 8;
        u32x2 pk; pk.x = lo; pk.y = hi;
        *reinterpret_cast<u32x2*>(tb + byteoff) = pk;
      }
    int h = colw / 192;
    int d0 = cmod - 128;                          // 0 or 32
    int b = m0 >> 11;
    int sbase = m0 & (SEQ - 1);
    uint16_t* vbase = Vt + ((size_t)(b * NH + h) * DH + d0) * SEQ + sbase + (lane & 7) * 8;
#pragma unroll
    for (int p = 0; p < 4; ++p) {
      int dl = p * 8 + (lane >> 3);               // 0..31
      u32x4 rv = *reinterpret_cast<const u32x4*>(
          tb + dl * 128 + (((lane & 7) ^ (dl & 7)) * 16));
      *reinterpret_cast<u32x4*>(vbase + (size_t)dl * SEQ) = rv;
    }
  } else {
    // q (scaled) / k rows -> qkv
    float sc = ((cmod >> 6) == 0) ? QSCALE : 1.0f;
#pragma unroll
    for (int i = 0; i < 4; ++i) {
      int row = m0 + i * 16 + l4 * 4;
#pragma unroll
      for (int j = 0; j < 2; ++j) {
        int col = colw + j * 16 + l15;
#pragma unroll
        for (int jj = 0; jj < 4; ++jj)
          C[(size_t)(row + jj) * N_QKV + col] = f2bf(acc[i][j][jj] * sc);
      }
    }
  }
}

// ---------------- Flash attention, split-KV, KVBLK=64 (R8 skeleton, hoisted addressing) ----
// LDS map (one array, 40 KB): K0@0  K1@8192  V0@16384  V1@24576  Pl@32768 (w*2048)
#define NT (SEQ / 64)          // 32 kv tiles total

__global__ __launch_bounds__(256)
void attn(const uint16_t* __restrict__ qkv, const uint16_t* __restrict__ VtG,
          float* __restrict__ Po,      // [split][16][2048][64] f32 unnormalized
          float2* __restrict__ Pml) {  // [split][16][2048] (m, l)
  __shared__ __align__(16) char SM[40960];

  const int t = threadIdx.x;
  const int lane = t & 63;
  const int w = t >> 6;
  const int l15 = lane & 15, l4 = lane >> 4;
  const int m7 = l15 & 7;
  const int bh = blockIdx.x;               // head-major: XCD bh%8 owns 2 heads' K/V
  const int b = bh >> 3, h = bh & 7;
  const int qw = blockIdx.y * 64 + w * 16;
  const int half = blockIdx.z;
  const int tph = NT / gridDim.z;
  const int t0 = half * tph;

  // Q fragments (pre-scaled by QSCALE in GEMM epilogue)
  bf16x8 qf[2];
  {
    const uint16_t* qp = qkv + (size_t)(b * SEQ + qw + l15) * N_QKV + h * 192;
#pragma unroll
    for (int kk = 0; kk < 2; ++kk)
      qf[kk] = *reinterpret_cast<const bf16x8*>(qp + kk * 32 + l4 * 8);
  }

  // ---- hoisted per-lane LDS addresses ----
  // all K/V/P fragment reads: base a0 = l15*128 + ((l4 ^ m7))*16 ; kk=1 flips bit6
  const uint32_t a0 = (uint32_t)(l15 * 128 + ((l4 ^ m7) * 16));
  const uint32_t a1 = a0 ^ 64;
  const char* const plbase = SM + 32768 + w * 2048;
  const char* const pp0 = plbase + a0;
  const char* const pp1 = plbase + a1;
  // P write pointers (c = 0..3), fixed across tiles
  char* const pwb = SM + 32768 + w * 2048 + l15 * 128 + (l4 & 1) * 8;
  const int hh = l4 >> 1;
  char* const pw0 = pwb + (((0 + hh) ^ m7) * 16);
  char* const pw1 = pwb + (((2 + hh) ^ m7) * 16);
  char* const pw2 = pwb + (((4 + hh) ^ m7) * 16);
  char* const pw3 = pwb + (((6 + hh) ^ m7) * 16);

  // ---- staging pointers (advance by constant per tile) ----
  const int r0 = t >> 3;                   // 0..31
  const int sl8 = (t & 7) ^ (r0 & 7);
  const uint16_t* kg = qkv + (size_t)b * SEQ * N_QKV + h * 192 + 64
                     + (size_t)(t0 * 64 + r0) * N_QKV + sl8 * 8;
  const uint16_t* vg = VtG + (size_t)bh * DH * SEQ
                     + (size_t)r0 * SEQ + t0 * 64 + sl8 * 8;
  const uint32_t t16 = (uint32_t)t * 16;

  auto stage2 = [&](int buf) {
    char* dk = SM + buf * 8192 + t16;
    gload_lds16(kg, dk);
    gload_lds16(kg + 32 * N_QKV, dk + 4096);
    gload_lds16(vg, dk + 16384);
    gload_lds16(vg + 32 * SEQ, dk + 20480);
    kg += 64 * N_QKV;
    vg += 64;
  };

  f32x4 ot[4] = {};                        // ot[f][jj] = O[d=f*16+l4*4+jj][q=l15]
  float mrow = -1e30f;                     // q-group-uniform running max (log2 dom)
  float lrow = 0.0f;                       // PER-LANE partial denominator

  stage2(0);
  for (int rel = 0; rel < tph; ++rel) {
    __syncthreads();                       // vmcnt(0) drain + barrier: tile rel ready
    if (rel + 1 < tph) stage2((rel + 1) & 1);
    const char* kb0 = SM + (rel & 1) * 8192 + a0;
    const char* kb1 = SM + (rel & 1) * 8192 + a1;

    // S^T = K @ Q^T : s[c] rows = key c*16+l4*4+jj, col = q = l15
    f32x4 s[4] = {};
    __builtin_amdgcn_s_setprio(1);
#pragma unroll
    for (int c = 0; c < 4; ++c) {
      bf16x8 kf0 = *reinterpret_cast<const bf16x8*>(kb0 + c * 2048);
      s[c] = __builtin_amdgcn_mfma_f32_16x16x32_bf16(kf0, qf[0], s[c], 0, 0, 0);
      bf16x8 kf1 = *reinterpret_cast<const bf16x8*>(kb1 + c * 2048);
      s[c] = __builtin_amdgcn_mfma_f32_16x16x32_bf16(kf1, qf[1], s[c], 0, 0, 0);
    }
    __builtin_amdgcn_s_setprio(0);

    // per-lane max over this lane's 16 keys (no cross-lane in common path)
    float pmax = fmaxf(fmaxf(fmaxf(s[0][0], s[0][1]), fmaxf(s[0][2], s[0][3])),
                       fmaxf(fmaxf(s[1][0], s[1][1]), fmaxf(s[1][2], s[1][3])));
    pmax = fmaxf(pmax,
                 fmaxf(fmaxf(fmaxf(s[2][0], s[2][1]), fmaxf(s[2][2], s[2][3])),
                       fmaxf(fmaxf(s[3][0], s[3][1]), fmaxf(s[3][2], s[3][3]))));

    if (!__all(pmax - mrow <= 11.0f)) {    // defer-max: rescale rarely
      float vm = pmax;
      vm = fmaxf(vm, __shfl_xor(vm, 16, 64));
      vm = fmaxf(vm, __shfl_xor(vm, 32, 64));   // q-group max (uniform per q)
      float mn = fmaxf(mrow, vm);
      float darg = mrow - mn;
      float sc;
      asm("v_exp_f32 %0, %1" : "=v"(sc) : "v"(darg));
      mrow = mn;
#pragma unroll
      for (int f = 0; f < 4; ++f)
#pragma unroll
        for (int jj = 0; jj < 4; ++jj) ot[f][jj] *= sc;
      lrow *= sc;
    }

    float p[16];
#pragma unroll
    for (int c = 0; c < 4; ++c)
#pragma unroll
      for (int jj = 0; jj < 4; ++jj) {
        float arg = s[c][jj] - mrow;
        float e;
        asm("v_exp_f32 %0, %1" : "=v"(e) : "v"(arg));   // 2^x (log2-domain scores)
        p[c * 4 + jj] = e;
      }
    float a0s = (p[0] + p[1]) + (p[2] + p[3]);
    float a1s = (p[4] + p[5]) + (p[6] + p[7]);
    float a2s = (p[8] + p[9]) + (p[10] + p[11]);
    float a3s = (p[12] + p[13]) + (p[14] + p[15]);
    lrow += (a0s + a1s) + (a2s + a3s);     // per-lane partial; reduced in epilogue

    // pack P (4 consecutive keys per c), one b64 store per c (fixed pointers)
    {
      uint32_t lo, hi; u32x2 pk;
      asm("v_cvt_pk_bf16_f32 %0, %1, %2" : "=v"(lo) : "v"(p[0]), "v"(p[1]));
      asm("v_cvt_pk_bf16_f32 %0, %1, %2" : "=v"(hi) : "v"(p[2]), "v"(p[3]));
      pk.x = lo; pk.y = hi; *reinterpret_cast<u32x2*>(pw0) = pk;
      asm("v_cvt_pk_bf16_f32 %0, %1, %2" : "=v"(lo) : "v"(p[4]), "v"(p[5]));
      asm("v_cvt_pk_bf16_f32 %0, %1, %2" : "=v"(hi) : "v"(p[6]), "v"(p[7]));
      pk.x = lo; pk.y = hi; *reinterpret_cast<u32x2*>(pw1) = pk;
      asm("v_cvt_pk_bf16_f32 %0, %1, %2" : "=v"(lo) : "v"(p[8]), "v"(p[9]));
      asm("v_cvt_pk_bf16_f32 %0, %1, %2" : "=v"(hi) : "v"(p[10]), "v"(p[11]));
      pk.x = lo; pk.y = hi; *reinterpret_cast<u32x2*>(pw2) = pk;
      asm("v_cvt_pk_bf16_f32 %0, %1, %2" : "=v"(lo) : "v"(p[12]), "v"(p[13]));
      asm("v_cvt_pk_bf16_f32 %0, %1, %2" : "=v"(hi) : "v"(p[14]), "v"(p[15]));
      pk.x = lo; pk.y = hi; *reinterpret_cast<u32x2*>(pw3) = pk;
    }

    // O^T += V @ P^T : A = V frag (row=d), B = P frag (col=q)
    bf16x8 pa0 = *reinterpret_cast<const bf16x8*>(pp0);
    bf16x8 pa1 = *reinterpret_cast<const bf16x8*>(pp1);
    __builtin_amdgcn_s_setprio(1);
#pragma unroll
    for (int f = 0; f < 4; ++f) {
      bf16x8 vf0 = *reinterpret_cast<const bf16x8*>(kb0 + 16384 + f * 2048);
      ot[f] = __builtin_amdgcn_mfma_f32_16x16x32_bf16(vf0, pa0, ot[f], 0, 0, 0);
      bf16x8 vf1 = *reinterpret_cast<const bf16x8*>(kb1 + 16384 + f * 2048);
      ot[f] = __builtin_amdgcn_mfma_f32_16x16x32_bf16(vf1, pa1, ot[f], 0, 0, 0);
    }
    __builtin_amdgcn_s_setprio(0);
  }

  // epilogue: reduce per-lane denominator partials across the q-group (2 shuffles)
  lrow += __shfl_xor(lrow, 16, 64);
  lrow += __shfl_xor(lrow, 32, 64);

  // write partials: coalesced f32x4 (4 consecutive d per reg)
  float* pob = Po + ((size_t)(half * 16 + bh) * SEQ) * DH + (size_t)(qw + l15) * DH;
#pragma unroll
  for (int f = 0; f < 4; ++f)
    *reinterpret_cast<f32x4*>(pob + f * 16 + l4 * 4) = ot[f];
  if (lane < 16) {
    float2 ml; ml.x = mrow; ml.y = lrow;
    Pml[(size_t)(half * 16 + bh) * SEQ + qw + lane] = ml;
  }
}

// ---------------- combine partials -> out[b][q][h*64+d] ----
__global__ __launch_bounds__(256)
void attn_combine(const float* __restrict__ Po, const float2* __restrict__ Pml,
                  float* __restrict__ out, int nsplit) {
  int idx = blockIdx.x * 256 + threadIdx.x;   // 16bh * 2048q * 16 d4
  int d4 = idx & 15;
  int q = (idx >> 4) & (SEQ - 1);
  int bh = idx >> 15;
  int b = bh >> 3, h = bh & 7;

  float m = -1e30f;
  for (int s = 0; s < nsplit; ++s)
    m = fmaxf(m, Pml[(size_t)(s * 16 + bh) * SEQ + q].x);
  float den = 0.0f;
  f32x4 acc = {};
  for (int s = 0; s < nsplit; ++s) {
    float2 ml = Pml[(size_t)(s * 16 + bh) * SEQ + q];
    float a = exp2f(ml.x - m);
    den += ml.y * a;
    f32x4 ov = *reinterpret_cast<const f32x4*>(
        Po + ((size_t)(s * 16 + bh) * SEQ + q) * DH + d4 * 4);
#pragma unroll
    for (int i = 0; i < 4; ++i) acc[i] += ov[i] * a;
  }
  float rden = 1.0f / den;
  f32x4 res;
#pragma unroll
  for (int i = 0; i < 4; ++i) res[i] = acc[i] * rden;
  *reinterpret_cast<f32x4*>(out + ((size_t)(b * SEQ + q) * HD) + h * 64 + d4 * 4) = res;
}

extern "C" void kernel_launch(void* const* d_in, const int* in_sizes, int n_in,
                              void* d_out, int out_size, void* d_ws, size_t ws_size,
                              hipStream_t stream) {
  const float* x = (const float*)d_in[0];
  const float* Wq = (const float*)d_in[1];
  float* out = (float*)d_out;

  uint16_t* xb = (uint16_t*)d_ws;                       // 4096*512 bf16   (4 MB)
  uint16_t* Wb = xb + (size_t)M_TOTAL * K_DIM;          // 1536*512 bf16   (1.5 MB)
  uint16_t* qkv = Wb + (size_t)N_QKV * K_DIM;           // 4096*1536 bf16  (12.6 MB)
  uint16_t* vtg = qkv + (size_t)M_TOTAL * N_QKV;        // 16*64*2048 bf16 (4 MB)
  float* Po = (float*)(vtg + (size_t)16 * DH * SEQ);    // 2*16*2048*64 f32 (16.8 MB)
  float2* Pml = (float2*)(Po + (size_t)2 * 16 * SEQ * DH);  // 2*16*2048 f32x2 (0.5 MB)
  size_t base = (size_t)((char*)Po - (char*)d_ws);
  size_t per_split = (size_t)16 * SEQ * DH * 4 + (size_t)16 * SEQ * 8;
  int nsplit = (ws_size >= base + 2 * per_split) ? 2 : 1;

  convert_all<<<(M_TOTAL * K_DIM / 4 + N_QKV * K_DIM / 4 + 255) / 256, 256, 0, stream>>>(
      x, Wq, xb, Wb);

  dim3 g1(N_QKV / BN, M_TOTAL / BM);
  qkv_gemm<<<g1, 256, 0, stream>>>(xb, Wb, qkv, vtg);

  dim3 g2(BATCH * NH, SEQ / 64, nsplit);
  attn<<<g2, 256, 0, stream>>>(qkv, vtg, Po, Pml);

  attn_combine<<<(16 * SEQ * 16) / 256, 256, 0, stream>>>(Po, Pml, out, nsplit);
}